// Round 2
// baseline (176.374 us; speedup 1.0000x reference)
//
#include <hip/hip_runtime.h>

// Problem constants (fixed by setup_inputs): B=4,T=32,H=224,W=224,C=3
namespace {
constexpr int B_ = 4, T_ = 32, H_ = 224, W_ = 224;
constexpr int HW_ = H_ * W_;              // 50176
constexpr int NPIX_ = B_ * T_ * HW_;      // 6422528
constexpr int N1_ = 79;                   // int(6422528*0.2*0.8 // 13005)
constexpr int N2_ = 9;                    // int(6422528*0.2*0.1 // 13005)
constexpr int NBOX_RW_ = N1_ + N2_;       // 88 boxes affect pixel output
constexpr int NBOX_M_  = N1_ + 2 * N2_;   // 97 boxes affect M
constexpr int HALF_T = 2, HALF_HW = 25;
}

// Kernel A: stage all 97 boxes in LDS, then each thread builds its (b,t)
// slice's rect lists. rects[s][0..c1) = R1 (mask_token), [N1..N1+c2) = R2
// (random_token, wins). Also writes M flags and gathers random_token.
__global__ __launch_bounds__(128) void build_slice_rects(
    const float* __restrict__ frames,
    const int* __restrict__ bb, const int* __restrict__ tt,
    const int* __restrict__ hh, const int* __restrict__ ww,
    const int* __restrict__ rb, const int* __restrict__ rt,
    const int* __restrict__ rh, const int* __restrict__ rw,
    int2* __restrict__ counts, int4* __restrict__ rects,
    float* __restrict__ rtok, float* __restrict__ Mout)
{
    __shared__ int lb[NBOX_M_], ltlo[NBOX_M_], lthi[NBOX_M_];
    __shared__ int4 lrect[NBOX_M_];

    int s = threadIdx.x;
    if (s == 0) {
        long idx = (((long)rb[0] * T_ + rt[0]) * H_ + rh[0]) * W_ + rw[0];
        rtok[0] = frames[idx * 3 + 0];
        rtok[1] = frames[idx * 3 + 1];
        rtok[2] = frames[idx * 3 + 2];
    }
    if (s < NBOX_M_) {
        lb[s]   = bb[s];
        ltlo[s] = max(tt[s] - HALF_T, 0);
        lthi[s] = min(tt[s] + HALF_T, T_ - 1);   // exclusive (ref uses size-1)
        int4 r;
        r.x = max(hh[s] - HALF_HW, 0);
        r.y = min(hh[s] + HALF_HW, H_ - 1);      // exclusive
        r.z = max(ww[s] - HALF_HW, 0);
        r.w = min(ww[s] + HALF_HW, W_ - 1);      // exclusive
        lrect[s] = r;
    }
    __syncthreads();

    int sb = s / T_, st = s % T_;
    int c1 = 0, c2 = 0;
    bool any = false;
    int4* rs = rects + s * NBOX_RW_;
    for (int i = 0; i < NBOX_M_; ++i) {
        if (lb[i] != sb || st < ltlo[i] || st >= lthi[i]) continue;
        any = true;
        if (i >= NBOX_RW_) continue;             // R3: M only
        if (i < N1_) rs[c1++] = lrect[i];
        else         rs[N1_ + c2++] = lrect[i];
    }
    counts[s] = make_int2(c1, c2);
    Mout[s] = any ? 1.0f : 0.0f;
}

// Kernel B: one thread per 8 pixels (24 floats = 6x float4). 224 % 8 == 0 so
// all 8 pixels share (slice,row); rect tests reduce to one interval->bitmask
// op per rect.
__global__ __launch_bounds__(256) void apply_mask(
    const float* __restrict__ frames, const float* __restrict__ mtok,
    const int2* __restrict__ counts, const int4* __restrict__ rects,
    const float* __restrict__ rtok, float* __restrict__ out)
{
    int gid = blockIdx.x * blockDim.x + threadIdx.x;
    int p0 = gid * 8;                         // grid exactly covers NPIX_/8

    const float4* fin = (const float4*)(frames + (long)p0 * 3);
    float4 f[6];
#pragma unroll
    for (int k = 0; k < 6; ++k) f[k] = fin[k];

    int s  = p0 / HW_;
    int hw = p0 - s * HW_;
    int h  = hw / W_;
    int w0 = hw - h * W_;

    int2 c = counts[s];
    const int4* rs = rects + s * NBOX_RW_;
    unsigned m1 = 0, m2 = 0;
    for (int j = 0; j < c.x; ++j) {           // R1: mask_token
        int4 r = rs[j];
        if (h >= r.x && h < r.y) {
            int lo = max(r.z - w0, 0), hi = min(r.w - w0, 8);
            if (hi > lo) m1 |= ((1u << (hi - lo)) - 1u) << lo;
        }
    }
    for (int j = 0; j < c.y; ++j) {           // R2: random_token, wins
        int4 r = rs[N1_ + j];
        if (h >= r.x && h < r.y) {
            int lo = max(r.z - w0, 0), hi = min(r.w - w0, 8);
            if (hi > lo) m2 |= ((1u << (hi - lo)) - 1u) << lo;
        }
    }

    if (m1 | m2) {
        float mt0 = mtok[0], mt1 = mtok[1], mt2 = mtok[2];
        float rt0 = rtok[0], rt1 = rtok[1], rt2 = rtok[2];
        float* v = (float*)f;
#pragma unroll
        for (int k = 0; k < 8; ++k) {
            bool b2 = (m2 >> k) & 1u, b1 = (m1 >> k) & 1u;
            v[k * 3 + 0] = b2 ? rt0 : (b1 ? mt0 : v[k * 3 + 0]);
            v[k * 3 + 1] = b2 ? rt1 : (b1 ? mt1 : v[k * 3 + 1]);
            v[k * 3 + 2] = b2 ? rt2 : (b1 ? mt2 : v[k * 3 + 2]);
        }
    }

    float4* fo = (float4*)(out + (long)p0 * 3);
#pragma unroll
    for (int k = 0; k < 6; ++k) fo[k] = f[k];
}

extern "C" void kernel_launch(void* const* d_in, const int* in_sizes, int n_in,
                              void* d_out, int out_size, void* d_ws, size_t ws_size,
                              hipStream_t stream)
{
    const float* frames = (const float*)d_in[0];
    const float* mtok   = (const float*)d_in[1];
    const int* b  = (const int*)d_in[2];
    const int* t  = (const int*)d_in[3];
    const int* h  = (const int*)d_in[4];
    const int* w  = (const int*)d_in[5];
    const int* rb = (const int*)d_in[6];
    const int* rt = (const int*)d_in[7];
    const int* rh = (const int*)d_in[8];
    const int* rw = (const int*)d_in[9];

    // ws layout: counts int2[128] (1KB) | rects int4[128][88] (176KB) | rtok f32[3]
    int2*  counts = (int2*)d_ws;
    int4*  rects  = (int4*)((char*)d_ws + 1024);
    float* rtok   = (float*)((char*)d_ws + 1024 + (size_t)128 * NBOX_RW_ * 16);

    float* out_frames = (float*)d_out;
    float* out_M      = out_frames + (long)NPIX_ * 3;   // (B,T) flags as floats

    build_slice_rects<<<1, 128, 0, stream>>>(frames, b, t, h, w, rb, rt, rh, rw,
                                             counts, rects, rtok, out_M);

    int nthreads = NPIX_ / 8;                 // 802816 = 3136 * 256
    apply_mask<<<nthreads / 256, 256, 0, stream>>>(frames, mtok, counts, rects,
                                                   rtok, out_frames);
}